// Round 3
// baseline (284.656 us; speedup 1.0000x reference)
//
#include <hip/hip_runtime.h>
#include <math.h>

#define TT 8
#define NTOK 12288
#define DD 256
#define NNODE 8192
#define NNODES 32768
#define CLEN 16
#define CDIM 64
#define CHUNK 2048
#define H1 128

typedef __bf16 bf16x8 __attribute__((ext_vector_type(8)));
typedef float f32x4 __attribute__((ext_vector_type(4)));

__device__ __forceinline__ float gelu_exact(float v) {
    return 0.5f * v * (1.0f + erff(v * 0.70710678118654752f));
}

__device__ __forceinline__ ushort f2bf(float f) {
    uint u = __float_as_uint(f);
    u += 0x7FFFu + ((u >> 16) & 1u);
    return (ushort)(u >> 16);
}
__device__ __forceinline__ float bf2f(ushort h) {
    return __uint_as_float(((uint)h) << 16);
}

// ---- Kernel 0: wt = g.*w1 split into bf16 hi/lo, chunk-tiled [8][128 col][32 k];
//      u[c] = colsum(wt), v[c] = sum_k b[k]*w1[k,c] (atomic f32, zeroed by memset) ----
__global__ __launch_bounds__(256) void k_split_w1(
    const float* __restrict__ w1, const float* __restrict__ ln1_g,
    const float* __restrict__ ln1_b,
    ushort* __restrict__ w1pre, float* __restrict__ uvec, float* __restrict__ vvec)
{
    const int e = blockIdx.x * 256 + threadIdx.x;   // 0..32767, e = k*128 + c
    const int k = e >> 7, c = e & 127;
    const float w = w1[e];
    const float wt = w * ln1_g[k];
    const ushort hi = f2bf(wt);
    const ushort lo = f2bf(wt - bf2f(hi));
    const int off = (((k >> 5) * 128 + c) << 5) + (k & 31);
    w1pre[off] = hi;
    w1pre[32768 + off] = lo;
    atomicAdd(&uvec[c], wt);
    atomicAdd(&vvec[c], ln1_b[k] * w);
}

// ---- Kernel 1: MFMA GEMM on RAW x (hi/lo bf16 split) -> LN folded into epilogue:
//      y[i,c] = r_i*(x@wt)[i,c] - r_i*m_i*u[c] + v[c]
// grid (128 rowblocks, 8 t), block 256 (4 waves). Block tile: 64 rows x 128 cols.
// Register prefetch: chunk k+1 global loads issued after barrier-1, consumed next iter.
__global__ __launch_bounds__(256) void k_ln_gemm(
    const float* __restrict__ x, const int* __restrict__ indices,
    const ushort* __restrict__ w1pre,
    const float* __restrict__ uvec, const float* __restrict__ vvec,
    float* __restrict__ y,
    int* __restrict__ cnt, int* __restrict__ slot0, int* __restrict__ slotsx,
    int* __restrict__ ovfcnt, int* __restrict__ ovf)
{
    const int t = blockIdx.y;
    const int rowBase = blockIdx.x * 64;
    const int tid = threadIdx.x;

    // row stride 40 bf16 (80 B): (row*20 + grp*4) mod 32 banks is uniform for
    // the 16x16x32 frag read pattern (lane&15 = row, lane>>4 = k-group).
    __shared__ ushort Ah[64 * 40];    // 5 KiB
    __shared__ ushort Al[64 * 40];    // 5 KiB
    __shared__ ushort Bh[128 * 40];   // 10 KiB
    __shared__ ushort Bl[128 * 40];   // 10 KiB
    __shared__ float red[64][4][2];
    __shared__ float mS[64], rS[64];
    __shared__ float uS[128], vS[128];

    const float* xblk = x + ((size_t)t * NTOK + rowBase) * DD;

    // staging roles
    const int srow  = tid & 63;      // A: one row, 8 k per thread
    const int skq   = tid >> 6;      // A: k-octet
    const int bcol  = tid >> 1;      // B: one col
    const int bhalf = tid & 1;       // B: 16-k half

    // ---- prefetch chunk 0 into registers (issued before everything else) ----
    const float* xrow = xblk + (size_t)srow * DD;
    float4 pa0 = *(const float4*)(xrow + skq * 8);
    float4 pa1 = *(const float4*)(xrow + skq * 8 + 4);
    const ushort* srcH0 = w1pre + (bcol * 32 + bhalf * 16);
    uint4 pbh0 = *(const uint4*)srcH0;
    uint4 pbh1 = *(const uint4*)(srcH0 + 8);
    uint4 pbl0 = *(const uint4*)(srcH0 + 32768);
    uint4 pbl1 = *(const uint4*)(srcH0 + 32768 + 8);

    // per-node row recording (64 rows of this block)
    if (tid < 64) {
        const int i = rowBase + tid;
        const int node = indices[t * NNODE + i];
        const int g = t * NNODES + node;
        const int pos = atomicAdd(&cnt[g], 1);
        if (pos == 0) slot0[g] = i;
        else if (pos <= 15) slotsx[(size_t)g * 15 + (pos - 1)] = i;
        else {
            const int op = atomicAdd(&ovfcnt[t], 1);
            ovf[t * NNODE + op] = (node << 13) | i;
        }
    }
    // stage u,v for epilogue
    if (tid < 128) { uS[tid] = uvec[tid]; vS[tid] = vvec[tid]; }

    // LN stats per row (4 threads/row) — needed only in the epilogue now
    {
        const int row = tid >> 2, q = tid & 3;
        const float* xr = xblk + (size_t)row * DD;
        float s = 0.f, ss = 0.f;
        #pragma unroll
        for (int u = 0; u < 16; ++u) {
            const float4 v = *(const float4*)(xr + (u * 4 + q) * 4);
            s  += v.x + v.y + v.z + v.w;
            ss += v.x*v.x + v.y*v.y + v.z*v.z + v.w*v.w;
        }
        red[row][q][0] = s;
        red[row][q][1] = ss;
    }
    __syncthreads();
    if (tid < 64) {
        const float s  = red[tid][0][0] + red[tid][1][0] + red[tid][2][0] + red[tid][3][0];
        const float ss = red[tid][0][1] + red[tid][1][1] + red[tid][2][1] + red[tid][3][1];
        const float m = s * (1.0f / 256.0f);
        const float var = ss * (1.0f / 256.0f) - m * m;
        mS[tid] = m;
        rS[tid] = rsqrtf(var + 1e-5f);
    }
    // no barrier needed here: mS/rS consumed only after the loop's barriers

    const int lane = tid & 63;
    const int wv   = tid >> 6;       // wave id: owns cols wv*32 .. wv*32+31
    const int arow = lane & 15;      // frag index (A: row, B: col)
    const int kg   = lane >> 4;      // k-group 0..3 (8 contiguous k each)

    f32x4 acc[4][2];
    #pragma unroll
    for (int rt = 0; rt < 4; ++rt)
        #pragma unroll
        for (int ct = 0; ct < 2; ++ct)
            acc[rt][ct] = (f32x4){0.f, 0.f, 0.f, 0.f};

    #pragma unroll
    for (int kc = 0; kc < 8; ++kc) {
        // ---- split A regs (raw x, no LN) -> LDS ----
        {
            const float xv[8] = {pa0.x, pa0.y, pa0.z, pa0.w, pa1.x, pa1.y, pa1.z, pa1.w};
            uint hp[4], lp[4];
            #pragma unroll
            for (int j = 0; j < 4; ++j) {
                const float a0 = xv[2*j], a1 = xv[2*j+1];
                const ushort h0 = f2bf(a0), h1 = f2bf(a1);
                const ushort l0 = f2bf(a0 - bf2f(h0)), l1 = f2bf(a1 - bf2f(h1));
                hp[j] = (uint)h0 | ((uint)h1 << 16);
                lp[j] = (uint)l0 | ((uint)l1 << 16);
            }
            *(uint4*)&Ah[srow * 40 + skq * 8] = make_uint4(hp[0], hp[1], hp[2], hp[3]);
            *(uint4*)&Al[srow * 40 + skq * 8] = make_uint4(lp[0], lp[1], lp[2], lp[3]);
        }
        // ---- store pre-split B regs -> LDS ----
        {
            const int d = bcol * 40 + bhalf * 16;
            *(uint4*)&Bh[d]     = pbh0;
            *(uint4*)&Bh[d + 8] = pbh1;
            *(uint4*)&Bl[d]     = pbl0;
            *(uint4*)&Bl[d + 8] = pbl1;
        }
        __syncthreads();

        // ---- issue next chunk's global loads (latency hides under MFMA) ----
        if (kc < 7) {
            const int k0 = (kc + 1) * 32 + skq * 8;
            pa0 = *(const float4*)(xrow + k0);
            pa1 = *(const float4*)(xrow + k0 + 4);
            const ushort* srcH = w1pre + (((kc + 1) * 128 + bcol) * 32 + bhalf * 16);
            pbh0 = *(const uint4*)srcH;
            pbh1 = *(const uint4*)(srcH + 8);
            pbl0 = *(const uint4*)(srcH + 32768);
            pbl1 = *(const uint4*)(srcH + 32768 + 8);
        }

        // ---- frags + MFMA ----
        bf16x8 a_h[4], a_l[4], b_h[2], b_l[2];
        #pragma unroll
        for (int rt = 0; rt < 4; ++rt) {
            const int o = (rt * 16 + arow) * 40 + kg * 8;
            a_h[rt] = *(const bf16x8*)&Ah[o];
            a_l[rt] = *(const bf16x8*)&Al[o];
        }
        #pragma unroll
        for (int ct = 0; ct < 2; ++ct) {
            const int o = (wv * 32 + ct * 16 + arow) * 40 + kg * 8;
            b_h[ct] = *(const bf16x8*)&Bh[o];
            b_l[ct] = *(const bf16x8*)&Bl[o];
        }
        #pragma unroll
        for (int rt = 0; rt < 4; ++rt)
            #pragma unroll
            for (int ct = 0; ct < 2; ++ct) {
                acc[rt][ct] = __builtin_amdgcn_mfma_f32_16x16x32_bf16(a_h[rt], b_h[ct], acc[rt][ct], 0, 0, 0);
                acc[rt][ct] = __builtin_amdgcn_mfma_f32_16x16x32_bf16(a_h[rt], b_l[ct], acc[rt][ct], 0, 0, 0);
                acc[rt][ct] = __builtin_amdgcn_mfma_f32_16x16x32_bf16(a_l[rt], b_h[ct], acc[rt][ct], 0, 0, 0);
            }
        __syncthreads();
    }

    // ---- epilogue: LN correction + store.
    //      C/D layout col=lane&15, row=(lane>>4)*4+reg ----
    #pragma unroll
    for (int rt = 0; rt < 4; ++rt) {
        const int rloc = rt * 16 + kg * 4;
        const int grow = rowBase + rloc;
        #pragma unroll
        for (int ct = 0; ct < 2; ++ct) {
            const int gcol = wv * 32 + ct * 16 + arow;
            const float uu = uS[gcol];
            const float vb = vS[gcol];
            float* dst = y + (((size_t)t * NNODE + grow) << 7) + gcol;
            #pragma unroll
            for (int j = 0; j < 4; ++j) {
                const float m = mS[rloc + j], r = rS[rloc + j];
                dst[(size_t)j << 7] = r * (acc[rt][ct][j] - m * uu) + vb;
            }
        }
    }
}

// ---- Kernel 2: per-node sums -> gelu -> chunk sum into sbuf ----
// grid (sub 32, l 16, t 8) = 4096 blocks, block 256 = 2 node-lanes x 128 cols.
__global__ __launch_bounds__(256) void k_node_sum(
    const float* __restrict__ y, const float* __restrict__ b1,
    const int* __restrict__ cnt, const int* __restrict__ slot0,
    const int* __restrict__ slotsx,
    const int* __restrict__ ovfcnt, const int* __restrict__ ovf,
    float* __restrict__ sbuf)
{
    const int tid = threadIdx.x;
    const int sub = blockIdx.x, l = blockIdx.y, t = blockIdx.z;
    const int base = l * CHUNK + sub * 64;       // first node of this block

    __shared__ int cS[64], s0S[64];
    __shared__ float redc[256];

    if (tid < 64) {
        cS[tid]  = cnt[t * NNODES + base + tid];
        s0S[tid] = slot0[t * NNODES + base + tid];
    }
    __syncthreads();

    const int c = tid & 127;     // column
    const int h = tid >> 7;      // node parity
    const float b1c = b1[c];
    const float geluB = gelu_exact(b1c);
    const float* ybase = y + (((size_t)t * NNODE) << 7) + c;

    float cs = 0.f;
    int zc = 0;

    for (int p = 0; p < 32; ++p) {
        const int nl = p * 2 + h;          // node-local 0..63 (uniform per wave)
        const int n = cS[nl];
        if (n == 0) { ++zc; continue; }
        float acc = b1c + ybase[(size_t)s0S[nl] << 7];
        if (n > 1) {
            const int m = n < 16 ? n : 16;
            const int* sx = slotsx + (size_t)(t * NNODES + base + nl) * 15;
            for (int j = 0; j < m - 1; ++j)
                acc += ybase[(size_t)sx[j] << 7];
            if (n > 16) {                   // ultra-rare overflow path
                int oc = ovfcnt[t]; if (oc > NNODE) oc = NNODE;
                const int node = base + nl;
                for (int e = 0; e < oc; ++e) {
                    const int v = ovf[t * NNODE + e];
                    if ((v >> 13) == node) acc += ybase[(size_t)(v & 8191) << 7];
                }
            }
        }
        cs += gelu_exact(acc);
    }
    cs += (float)zc * geluB;

    redc[tid] = cs;
    __syncthreads();
    if (tid < 128)
        atomicAdd(&sbuf[(t * CLEN + l) * H1 + c], redc[tid] + redc[tid + 128]);
}

// ---- Kernel 3: comp = sbuf @ w2 + 2048*b2 ; lnf ; lnd ; decoder MLP -> decRow ----
// grid 8 (per t), block 1024. wave == one 64-wide comp row -> shfl butterflies.
__global__ __launch_bounds__(1024) void k_decode(
    const float* __restrict__ sbuf, const float* __restrict__ w2,
    const float* __restrict__ b2,
    const float* __restrict__ lnf_g, const float* __restrict__ lnf_b,
    const float* __restrict__ lnd_g, const float* __restrict__ lnd_b,
    const float* __restrict__ dw1, const float* __restrict__ db1,
    const float* __restrict__ dw2, const float* __restrict__ db2,
    float* __restrict__ decRow)
{
    const int t = blockIdx.x, tid = threadIdx.x;
    __shared__ float wbuf[8192];          // staged weight chunk (32 KiB)
    __shared__ float sb[CLEN * H1];       // staged sbuf[t] (8 KiB)
    __shared__ float vv[CLEN][CDIM];
    __shared__ float hh[CLEN][H1];
    __shared__ float redA[16], redB[16];

    // stage sbuf[t] (2048 f) + w2 (8192 f)
    if (tid < 512) *(float4*)&sb[tid * 4] = *(const float4*)(sbuf + t * CLEN * H1 + tid * 4);
    #pragma unroll
    for (int u = 0; u < 2; ++u) {
        const int j4 = (tid + u * 1024) * 4;
        *(float4*)&wbuf[j4] = *(const float4*)(w2 + j4);
    }
    __syncthreads();

    // 1) comp element per thread: a = (sb @ w2)[l,cc] + CHUNK*b2[cc]
    const int l = tid >> 6, cc = tid & 63;   // wave == row l
    float a = (float)CHUNK * b2[cc];
    {
        const float* sp = sb + l * H1;
        for (int k = 0; k < H1; ++k) a += sp[k] * wbuf[k * CDIM + cc];
    }
    __syncthreads();                          // wbuf (w2) free

    // stage dw1 (8192 f) while lnf partials reduce
    #pragma unroll
    for (int u = 0; u < 2; ++u) {
        const int j4 = (tid + u * 1024) * 4;
        *(float4*)&wbuf[j4] = *(const float4*)(dw1 + j4);
    }
    // 2) lnf over 1024: wave butterfly (= row sum) then 16 partials
    float s = a, ss = a * a;
    #pragma unroll
    for (int off = 1; off < 64; off <<= 1) {
        s  += __shfl_xor(s, off);
        ss += __shfl_xor(ss, off);
    }
    if ((tid & 63) == 0) { redA[tid >> 6] = s; redB[tid >> 6] = ss; }
    __syncthreads();                          // partials + dw1 staged

    float st = 0.f, sst = 0.f;
    #pragma unroll
    for (int w = 0; w < 16; ++w) { st += redA[w]; sst += redB[w]; }
    const float mG = st * (1.0f / 1024.0f);
    const float rG = rsqrtf(sst * (1.0f / 1024.0f) - mG * mG + 1e-5f);
    const float vln = (a - mG) * rG * lnf_g[tid] + lnf_b[tid];

    // 3) lnd per 64-wide row: pure wave butterfly
    float s2 = vln, ss2 = vln * vln;
    #pragma unroll
    for (int off = 1; off < 64; off <<= 1) {
        s2  += __shfl_xor(s2, off);
        ss2 += __shfl_xor(ss2, off);
    }
    const float m2 = s2 * (1.0f / 64.0f);
    const float r2 = rsqrtf(ss2 * (1.0f / 64.0f) - m2 * m2 + 1e-5f);
    vv[l][cc] = (vln - m2) * r2 * lnd_g[cc] + lnd_b[cc];
    __syncthreads();                          // vv ready, wbuf = dw1 ready

    // 4) hh = gelu(vv @ dw1 + db1): 2048 outputs, 2 per thread
    #pragma unroll
    for (int u = 0; u < 2; ++u) {
        const int j = tid + u * 1024;
        const int lh = j >> 7, ch = j & 127;
        float acc = db1[ch];
        for (int k = 0; k < CDIM; ++k) acc += vv[lh][k] * wbuf[k * H1 + ch];
        hh[lh][ch] = gelu_exact(acc);
    }
    __syncthreads();                          // hh ready, wbuf free

    // 5) decRow = hh @ dw2 + db2, dw2 staged in four 64-col chunks (128x64 each)
    for (int chk = 0; chk < 4; ++chk) {
        const int c0 = chk * 64;
        #pragma unroll
        for (int u = 0; u < 2; ++u) {
            const int e = tid + u * 1024;         // 0..2047
            const int k = e >> 4, cq = e & 15;    // k<128, 16 float4 per row
            *(float4*)&wbuf[k * 64 + cq * 4] =
                *(const float4*)(dw2 + (size_t)k * DD + c0 + cq * 4);
        }
        __syncthreads();
        float acc = db2[c0 + cc];
        for (int k = 0; k < H1; ++k) acc += hh[l][k] * wbuf[k * 64 + cc];
        decRow[(t * CLEN + l) * DD + c0 + cc] = acc;
        __syncthreads();
    }
}

// ---- Kernel 4: out[t,i,:] = decRow[t, idx[t,i]>>11, :] for i<8192 else 0 ----
__global__ __launch_bounds__(256) void k_gather(
    const int* __restrict__ indices, const float* __restrict__ decRow,
    float* __restrict__ out)
{
    const int tid = threadIdx.x;
    const int r = blockIdx.x * 4 + (tid >> 6);
    const int c4 = tid & 63;
    const int t = r / NTOK;
    const int i = r - t * NTOK;
    float4 v = make_float4(0.f, 0.f, 0.f, 0.f);
    if (i < NNODE) {
        const int node = indices[t * NNODE + i];
        const int l = node >> 11;
        v = *(const float4*)(decRow + (t * CLEN + l) * DD + c4 * 4);
    }
    *(float4*)(out + (size_t)r * DD + c4 * 4) = v;
}

extern "C" void kernel_launch(void* const* d_in, const int* in_sizes, int n_in,
                              void* d_out, int out_size, void* d_ws, size_t ws_size,
                              hipStream_t stream)
{
    const float* x       = (const float*)d_in[0];
    const int*   indices = (const int*)d_in[1];
    const float* ln1_g   = (const float*)d_in[2];
    const float* ln1_b   = (const float*)d_in[3];
    const float* w1      = (const float*)d_in[4];
    const float* b1      = (const float*)d_in[5];
    const float* w2      = (const float*)d_in[6];
    const float* b2      = (const float*)d_in[7];
    const float* lnf_g   = (const float*)d_in[8];
    const float* lnf_b   = (const float*)d_in[9];
    const float* lnd_g   = (const float*)d_in[10];
    const float* lnd_b   = (const float*)d_in[11];
    const float* dw1     = (const float*)d_in[12];
    const float* db1     = (const float*)d_in[13];
    const float* dw2     = (const float*)d_in[14];
    const float* db2     = (const float*)d_in[15];
    float* out = (float*)d_out;

    char* ws = (char*)d_ws;
    // zeroed region: cnt (1 MiB) + ovfcnt (32 B) + sbuf (64 KiB) + u,v (1 KiB pad)
    int*    cnt    = (int*)ws;                            // 0x000000, 1 MiB
    int*    ovfcnt = (int*)(ws + 0x100000);               // 32 B
    float*  sbuf   = (float*)(ws + 0x100020);             // 64 KiB -> ends 0x110020
    float*  uvec   = (float*)(ws + 0x110020);             // 512 B
    float*  vvec   = (float*)(ws + 0x110220);             // 512 B -> ends 0x110420
    int*    slot0  = (int*)(ws + 0x120000);               // 1 MiB
    int*    slotsx = (int*)(ws + 0x220000);               // 15 MiB -> ends 0x1120000
    ushort* w1pre  = (ushort*)(ws + 0x1120000);           // 128 KiB (hi 64K + lo 64K)
    int*    ovf    = (int*)(ws + 0x11E0000);              // 256 KiB
    float*  decRow = (float*)(ws + 0x1220000);            // 128 KiB
    float*  y      = (float*)(ws + 0x1240000);            // 32 MiB

    hipMemsetAsync(ws, 0, 0x110420, stream);

    k_split_w1<<<128, 256, 0, stream>>>(w1, ln1_g, ln1_b, w1pre, uvec, vvec);
    k_ln_gemm<<<dim3(128, 8), 256, 0, stream>>>(x, indices, w1pre, uvec, vvec, y,
                                                cnt, slot0, slotsx, ovfcnt, ovf);
    k_node_sum<<<dim3(32, 16, 8), 256, 0, stream>>>(y, b1, cnt, slot0, slotsx,
                                                    ovfcnt, ovf, sbuf);
    k_decode<<<8, 1024, 0, stream>>>(sbuf, w2, b2, lnf_g, lnf_b, lnd_g, lnd_b,
                                     dw1, db1, dw2, db2, decRow);
    k_gather<<<24576, 256, 0, stream>>>(indices, decRow, out);
}

// Round 4
// 280.596 us; speedup vs baseline: 1.0145x; 1.0145x over previous
//
#include <hip/hip_runtime.h>
#include <math.h>

#define TT 8
#define NTOK 12288
#define DD 256
#define NNODE 8192
#define NNODES 32768
#define CLEN 16
#define CDIM 64
#define CHUNK 2048
#define H1 128

typedef __bf16 bf16x8 __attribute__((ext_vector_type(8)));
typedef float f32x4 __attribute__((ext_vector_type(4)));

__device__ __forceinline__ float gelu_exact(float v) {
    return 0.5f * v * (1.0f + erff(v * 0.70710678118654752f));
}

__device__ __forceinline__ ushort f2bf(float f) {
    uint u = __float_as_uint(f);
    u += 0x7FFFu + ((u >> 16) & 1u);
    return (ushort)(u >> 16);
}
__device__ __forceinline__ float bf2f(ushort h) {
    return __uint_as_float(((uint)h) << 16);
}

// ---- Kernel 0: wt = g.*w1 split into bf16 hi/lo, chunk-tiled [8][128 col][32 k];
//      u[c] = colsum(wt), v[c] = sum_k b[k]*w1[k,c] (atomic f32, zeroed by memset).
//      Lanes within a wave hit distinct c -> no intra-wave atomic serialization. ----
__global__ __launch_bounds__(256) void k_split_w1(
    const float* __restrict__ w1, const float* __restrict__ ln1_g,
    const float* __restrict__ ln1_b,
    ushort* __restrict__ w1pre, float* __restrict__ uvec, float* __restrict__ vvec)
{
    const int e = blockIdx.x * 256 + threadIdx.x;   // 0..32767, e = k*128 + c
    const int k = e >> 7, c = e & 127;
    const float w = w1[e];
    const float wt = w * ln1_g[k];
    const ushort hi = f2bf(wt);
    const ushort lo = f2bf(wt - bf2f(hi));
    const int off = (((k >> 5) * 128 + c) << 5) + (k & 31);
    w1pre[off] = hi;
    w1pre[32768 + off] = lo;
    atomicAdd(&uvec[c], wt);
    atomicAdd(&vvec[c], ln1_b[k] * w);
}

// ---- Kernel 1: MFMA GEMM on RAW x (hi/lo bf16 split), LN folded into epilogue:
//      y[i,c] = r_i*(x@wt)[i,c] - r_i*m_i*u[c] + v[c]
// grid (128 rowblocks, 8 t), block 256 (4 waves). Block tile: 64 rows x 128 cols.
// R2 loop structure (compiler-scheduled loads; no unroll pragma, no reg prefetch —
// R3's hand pipeline regressed +10us). LN stats accumulated from the staging
// registers -> x is read exactly once; no separate stats pass.
__global__ __launch_bounds__(256) void k_ln_gemm(
    const float* __restrict__ x, const int* __restrict__ indices,
    const ushort* __restrict__ w1pre,
    const float* __restrict__ uvec, const float* __restrict__ vvec,
    float* __restrict__ y,
    int* __restrict__ cnt, int* __restrict__ slot0, int* __restrict__ slotsx,
    int* __restrict__ ovfcnt, int* __restrict__ ovf)
{
    const int t = blockIdx.y;
    const int rowBase = blockIdx.x * 64;
    const int tid = threadIdx.x;

    // row stride 40 bf16 (80 B): (row*20 + grp*4) mod 32 banks is uniform for
    // the 16x16x32 frag read pattern (lane&15 = row, lane>>4 = k-group).
    __shared__ ushort Ah[64 * 40];    // 5 KiB
    __shared__ ushort Al[64 * 40];    // 5 KiB
    __shared__ ushort Bh[128 * 40];   // 10 KiB
    __shared__ ushort Bl[128 * 40];   // 10 KiB
    __shared__ float red[64][4][2];
    __shared__ float mS[64], rS[64];
    __shared__ float uS[128], vS[128];

    const float* xblk = x + ((size_t)t * NTOK + rowBase) * DD;

    // staging roles
    const int srow  = tid & 63;      // A: one row, 8 k per thread
    const int skq   = tid >> 6;      // A: k-octet
    const int bcol  = tid >> 1;      // B: one col
    const int bhalf = tid & 1;       // B: 16-k half
    const float* xrow = xblk + (size_t)srow * DD;

    // per-node row recording (64 rows of this block)
    if (tid < 64) {
        const int i = rowBase + tid;
        const int node = indices[t * NNODE + i];
        const int g = t * NNODES + node;
        const int pos = atomicAdd(&cnt[g], 1);
        if (pos == 0) slot0[g] = i;
        else if (pos <= 15) slotsx[(size_t)g * 15 + (pos - 1)] = i;
        else {
            const int op = atomicAdd(&ovfcnt[t], 1);
            ovf[t * NNODE + op] = (node << 13) | i;
        }
    }
    // stage u,v for epilogue
    if (tid < 128) { uS[tid] = uvec[tid]; vS[tid] = vvec[tid]; }

    const int lane = tid & 63;
    const int wv   = tid >> 6;       // wave id: owns cols wv*32 .. wv*32+31
    const int arow = lane & 15;      // frag index (A: row, B: col)
    const int kg   = lane >> 4;      // k-group 0..3 (8 contiguous k each)

    f32x4 acc[4][2];
    #pragma unroll
    for (int rt = 0; rt < 4; ++rt)
        #pragma unroll
        for (int ct = 0; ct < 2; ++ct)
            acc[rt][ct] = (f32x4){0.f, 0.f, 0.f, 0.f};

    float stS = 0.f, stSS = 0.f;     // LN stats partials for (srow, octet skq)

    for (int kc = 0; kc < 8; ++kc) {
        // ---- stage A: load raw x, accumulate stats, hi/lo split -> LDS ----
        {
            const int k0 = kc * 32 + skq * 8;
            const float4 v0 = *(const float4*)(xrow + k0);
            const float4 v1 = *(const float4*)(xrow + k0 + 4);
            const float xv[8] = {v0.x, v0.y, v0.z, v0.w, v1.x, v1.y, v1.z, v1.w};
            uint hp[4], lp[4];
            #pragma unroll
            for (int j = 0; j < 4; ++j) {
                const float a0 = xv[2*j], a1 = xv[2*j+1];
                stS  += a0 + a1;
                stSS += a0*a0 + a1*a1;
                const ushort h0 = f2bf(a0), h1 = f2bf(a1);
                const ushort l0 = f2bf(a0 - bf2f(h0)), l1 = f2bf(a1 - bf2f(h1));
                hp[j] = (uint)h0 | ((uint)h1 << 16);
                lp[j] = (uint)l0 | ((uint)l1 << 16);
            }
            *(uint4*)&Ah[srow * 40 + skq * 8] = make_uint4(hp[0], hp[1], hp[2], hp[3]);
            *(uint4*)&Al[srow * 40 + skq * 8] = make_uint4(lp[0], lp[1], lp[2], lp[3]);
        }
        // ---- stage B: copy pre-split g.*w1 chunk [128 col][32 k] hi/lo -> LDS ----
        {
            const ushort* srcH = w1pre + ((kc * 128 + bcol) * 32 + bhalf * 16);
            const uint4 h0 = *(const uint4*)srcH;
            const uint4 h1 = *(const uint4*)(srcH + 8);
            const uint4 l0 = *(const uint4*)(srcH + 32768);
            const uint4 l1 = *(const uint4*)(srcH + 32768 + 8);
            const int d = bcol * 40 + bhalf * 16;
            *(uint4*)&Bh[d]     = h0;
            *(uint4*)&Bh[d + 8] = h1;
            *(uint4*)&Bl[d]     = l0;
            *(uint4*)&Bl[d + 8] = l1;
        }
        __syncthreads();

        // ---- frags + MFMA ----
        bf16x8 a_h[4], a_l[4], b_h[2], b_l[2];
        #pragma unroll
        for (int rt = 0; rt < 4; ++rt) {
            const int o = (rt * 16 + arow) * 40 + kg * 8;
            a_h[rt] = *(const bf16x8*)&Ah[o];
            a_l[rt] = *(const bf16x8*)&Al[o];
        }
        #pragma unroll
        for (int ct = 0; ct < 2; ++ct) {
            const int o = (wv * 32 + ct * 16 + arow) * 40 + kg * 8;
            b_h[ct] = *(const bf16x8*)&Bh[o];
            b_l[ct] = *(const bf16x8*)&Bl[o];
        }
        #pragma unroll
        for (int rt = 0; rt < 4; ++rt)
            #pragma unroll
            for (int ct = 0; ct < 2; ++ct) {
                acc[rt][ct] = __builtin_amdgcn_mfma_f32_16x16x32_bf16(a_h[rt], b_h[ct], acc[rt][ct], 0, 0, 0);
                acc[rt][ct] = __builtin_amdgcn_mfma_f32_16x16x32_bf16(a_h[rt], b_l[ct], acc[rt][ct], 0, 0, 0);
                acc[rt][ct] = __builtin_amdgcn_mfma_f32_16x16x32_bf16(a_l[rt], b_h[ct], acc[rt][ct], 0, 0, 0);
            }
        __syncthreads();
    }

    // ---- reduce LN stats (4 octet-threads per row) ----
    red[srow][skq][0] = stS;
    red[srow][skq][1] = stSS;
    __syncthreads();
    if (tid < 64) {
        const float s  = red[tid][0][0] + red[tid][1][0] + red[tid][2][0] + red[tid][3][0];
        const float ss = red[tid][0][1] + red[tid][1][1] + red[tid][2][1] + red[tid][3][1];
        const float m = s * (1.0f / 256.0f);
        const float var = ss * (1.0f / 256.0f) - m * m;
        mS[tid] = m;
        rS[tid] = rsqrtf(var + 1e-5f);
    }
    __syncthreads();

    // ---- epilogue: LN correction + store. C/D layout col=lane&15, row=(lane>>4)*4+reg ----
    #pragma unroll
    for (int rt = 0; rt < 4; ++rt) {
        const int rloc = rt * 16 + kg * 4;
        const int grow = rowBase + rloc;
        #pragma unroll
        for (int ct = 0; ct < 2; ++ct) {
            const int gcol = wv * 32 + ct * 16 + arow;
            const float uu = uS[gcol];
            const float vb = vS[gcol];
            float* dst = y + (((size_t)t * NNODE + grow) << 7) + gcol;
            #pragma unroll
            for (int j = 0; j < 4; ++j) {
                const float m = mS[rloc + j], r = rS[rloc + j];
                dst[(size_t)j << 7] = r * (acc[rt][ct][j] - m * uu) + vb;
            }
        }
    }
}

// ---- Kernel 2: per-node sums -> gelu -> chunk sum into sbuf ----
// grid (sub 32, l 16, t 8) = 4096 blocks, block 256 = 2 node-lanes x 128 cols.
__global__ __launch_bounds__(256) void k_node_sum(
    const float* __restrict__ y, const float* __restrict__ b1,
    const int* __restrict__ cnt, const int* __restrict__ slot0,
    const int* __restrict__ slotsx,
    const int* __restrict__ ovfcnt, const int* __restrict__ ovf,
    float* __restrict__ sbuf)
{
    const int tid = threadIdx.x;
    const int sub = blockIdx.x, l = blockIdx.y, t = blockIdx.z;
    const int base = l * CHUNK + sub * 64;       // first node of this block

    __shared__ int cS[64], s0S[64];
    __shared__ float redc[256];

    if (tid < 64) {
        cS[tid]  = cnt[t * NNODES + base + tid];
        s0S[tid] = slot0[t * NNODES + base + tid];
    }
    __syncthreads();

    const int c = tid & 127;     // column
    const int h = tid >> 7;      // node parity
    const float b1c = b1[c];
    const float geluB = gelu_exact(b1c);
    const float* ybase = y + (((size_t)t * NNODE) << 7) + c;

    float cs = 0.f;
    int zc = 0;

    for (int p = 0; p < 32; ++p) {
        const int nl = p * 2 + h;          // node-local 0..63 (uniform per wave)
        const int n = cS[nl];
        if (n == 0) { ++zc; continue; }
        float acc = b1c + ybase[(size_t)s0S[nl] << 7];
        if (n > 1) {
            const int m = n < 16 ? n : 16;
            const int* sx = slotsx + (size_t)(t * NNODES + base + nl) * 15;
            for (int j = 0; j < m - 1; ++j)
                acc += ybase[(size_t)sx[j] << 7];
            if (n > 16) {                   // ultra-rare overflow path
                int oc = ovfcnt[t]; if (oc > NNODE) oc = NNODE;
                const int node = base + nl;
                for (int e = 0; e < oc; ++e) {
                    const int v = ovf[t * NNODE + e];
                    if ((v >> 13) == node) acc += ybase[(size_t)(v & 8191) << 7];
                }
            }
        }
        cs += gelu_exact(acc);
    }
    cs += (float)zc * geluB;

    redc[tid] = cs;
    __syncthreads();
    if (tid < 128)
        atomicAdd(&sbuf[(t * CLEN + l) * H1 + c], redc[tid] + redc[tid + 128]);
}

// ---- Kernel 3: comp = sbuf @ w2 + 2048*b2 ; lnf ; lnd ; decoder MLP -> decRow ----
// grid 8 (per t), block 1024. wave == one 64-wide comp row -> shfl butterflies.
__global__ __launch_bounds__(1024) void k_decode(
    const float* __restrict__ sbuf, const float* __restrict__ w2,
    const float* __restrict__ b2,
    const float* __restrict__ lnf_g, const float* __restrict__ lnf_b,
    const float* __restrict__ lnd_g, const float* __restrict__ lnd_b,
    const float* __restrict__ dw1, const float* __restrict__ db1,
    const float* __restrict__ dw2, const float* __restrict__ db2,
    float* __restrict__ decRow)
{
    const int t = blockIdx.x, tid = threadIdx.x;
    __shared__ float wbuf[8192];          // staged weight chunk (32 KiB)
    __shared__ float sb[CLEN * H1];       // staged sbuf[t] (8 KiB)
    __shared__ float vv[CLEN][CDIM];
    __shared__ float hh[CLEN][H1];
    __shared__ float redA[16], redB[16];

    // stage sbuf[t] (2048 f) + w2 (8192 f)
    if (tid < 512) *(float4*)&sb[tid * 4] = *(const float4*)(sbuf + t * CLEN * H1 + tid * 4);
    #pragma unroll
    for (int u = 0; u < 2; ++u) {
        const int j4 = (tid + u * 1024) * 4;
        *(float4*)&wbuf[j4] = *(const float4*)(w2 + j4);
    }
    __syncthreads();

    // 1) comp element per thread: a = (sb @ w2)[l,cc] + CHUNK*b2[cc]
    const int l = tid >> 6, cc = tid & 63;   // wave == row l
    float a = (float)CHUNK * b2[cc];
    {
        const float* sp = sb + l * H1;
        for (int k = 0; k < H1; ++k) a += sp[k] * wbuf[k * CDIM + cc];
    }
    __syncthreads();                          // wbuf (w2) free

    // stage dw1 (8192 f) while lnf partials reduce
    #pragma unroll
    for (int u = 0; u < 2; ++u) {
        const int j4 = (tid + u * 1024) * 4;
        *(float4*)&wbuf[j4] = *(const float4*)(dw1 + j4);
    }
    // 2) lnf over 1024: wave butterfly (= row sum) then 16 partials
    float s = a, ss = a * a;
    #pragma unroll
    for (int off = 1; off < 64; off <<= 1) {
        s  += __shfl_xor(s, off);
        ss += __shfl_xor(ss, off);
    }
    if ((tid & 63) == 0) { redA[tid >> 6] = s; redB[tid >> 6] = ss; }
    __syncthreads();                          // partials + dw1 staged

    float st = 0.f, sst = 0.f;
    #pragma unroll
    for (int w = 0; w < 16; ++w) { st += redA[w]; sst += redB[w]; }
    const float mG = st * (1.0f / 1024.0f);
    const float rG = rsqrtf(sst * (1.0f / 1024.0f) - mG * mG + 1e-5f);
    const float vln = (a - mG) * rG * lnf_g[tid] + lnf_b[tid];

    // 3) lnd per 64-wide row: pure wave butterfly
    float s2 = vln, ss2 = vln * vln;
    #pragma unroll
    for (int off = 1; off < 64; off <<= 1) {
        s2  += __shfl_xor(s2, off);
        ss2 += __shfl_xor(ss2, off);
    }
    const float m2 = s2 * (1.0f / 64.0f);
    const float r2 = rsqrtf(ss2 * (1.0f / 64.0f) - m2 * m2 + 1e-5f);
    vv[l][cc] = (vln - m2) * r2 * lnd_g[cc] + lnd_b[cc];
    __syncthreads();                          // vv ready, wbuf = dw1 ready

    // 4) hh = gelu(vv @ dw1 + db1): 2048 outputs, 2 per thread
    #pragma unroll
    for (int u = 0; u < 2; ++u) {
        const int j = tid + u * 1024;
        const int lh = j >> 7, ch = j & 127;
        float acc = db1[ch];
        for (int k = 0; k < CDIM; ++k) acc += vv[lh][k] * wbuf[k * H1 + ch];
        hh[lh][ch] = gelu_exact(acc);
    }
    __syncthreads();                          // hh ready, wbuf free

    // 5) decRow = hh @ dw2 + db2, dw2 staged in four 64-col chunks (128x64 each)
    for (int chk = 0; chk < 4; ++chk) {
        const int c0 = chk * 64;
        #pragma unroll
        for (int u = 0; u < 2; ++u) {
            const int e = tid + u * 1024;         // 0..2047
            const int k = e >> 4, cq = e & 15;    // k<128, 16 float4 per row
            *(float4*)&wbuf[k * 64 + cq * 4] =
                *(const float4*)(dw2 + (size_t)k * DD + c0 + cq * 4);
        }
        __syncthreads();
        float acc = db2[c0 + cc];
        for (int k = 0; k < H1; ++k) acc += hh[l][k] * wbuf[k * 64 + cc];
        decRow[(t * CLEN + l) * DD + c0 + cc] = acc;
        __syncthreads();
    }
}

// ---- Kernel 4: out[t,i,:] = decRow[t, idx[t,i]>>11, :] for i<8192 else 0 ----
__global__ __launch_bounds__(256) void k_gather(
    const int* __restrict__ indices, const float* __restrict__ decRow,
    float* __restrict__ out)
{
    const int tid = threadIdx.x;
    const int r = blockIdx.x * 4 + (tid >> 6);
    const int c4 = tid & 63;
    const int t = r / NTOK;
    const int i = r - t * NTOK;
    float4 v = make_float4(0.f, 0.f, 0.f, 0.f);
    if (i < NNODE) {
        const int node = indices[t * NNODE + i];
        const int l = node >> 11;
        v = *(const float4*)(decRow + (t * CLEN + l) * DD + c4 * 4);
    }
    *(float4*)(out + (size_t)r * DD + c4 * 4) = v;
}

extern "C" void kernel_launch(void* const* d_in, const int* in_sizes, int n_in,
                              void* d_out, int out_size, void* d_ws, size_t ws_size,
                              hipStream_t stream)
{
    const float* x       = (const float*)d_in[0];
    const int*   indices = (const int*)d_in[1];
    const float* ln1_g   = (const float*)d_in[2];
    const float* ln1_b   = (const float*)d_in[3];
    const float* w1      = (const float*)d_in[4];
    const float* b1      = (const float*)d_in[5];
    const float* w2      = (const float*)d_in[6];
    const float* b2      = (const float*)d_in[7];
    const float* lnf_g   = (const float*)d_in[8];
    const float* lnf_b   = (const float*)d_in[9];
    const float* lnd_g   = (const float*)d_in[10];
    const float* lnd_b   = (const float*)d_in[11];
    const float* dw1     = (const float*)d_in[12];
    const float* db1     = (const float*)d_in[13];
    const float* dw2     = (const float*)d_in[14];
    const float* db2     = (const float*)d_in[15];
    float* out = (float*)d_out;

    char* ws = (char*)d_ws;
    // zeroed region: cnt (1 MiB) + ovfcnt (32 B) + sbuf (64 KiB) + u,v (1 KiB pad)
    int*    cnt    = (int*)ws;                            // 0x000000, 1 MiB
    int*    ovfcnt = (int*)(ws + 0x100000);               // 32 B
    float*  sbuf   = (float*)(ws + 0x100020);             // 64 KiB -> ends 0x110020
    float*  uvec   = (float*)(ws + 0x110020);             // 512 B
    float*  vvec   = (float*)(ws + 0x110220);             // 512 B -> ends 0x110420
    int*    slot0  = (int*)(ws + 0x120000);               // 1 MiB
    int*    slotsx = (int*)(ws + 0x220000);               // 15 MiB -> ends 0x1120000
    ushort* w1pre  = (ushort*)(ws + 0x1120000);           // 128 KiB (hi 64K + lo 64K)
    int*    ovf    = (int*)(ws + 0x11E0000);              // 256 KiB
    float*  decRow = (float*)(ws + 0x1220000);            // 128 KiB
    float*  y      = (float*)(ws + 0x1240000);            // 32 MiB

    hipMemsetAsync(ws, 0, 0x110420, stream);

    k_split_w1<<<128, 256, 0, stream>>>(w1, ln1_g, ln1_b, w1pre, uvec, vvec);
    k_ln_gemm<<<dim3(128, 8), 256, 0, stream>>>(x, indices, w1pre, uvec, vvec, y,
                                                cnt, slot0, slotsx, ovfcnt, ovf);
    k_node_sum<<<dim3(32, 16, 8), 256, 0, stream>>>(y, b1, cnt, slot0, slotsx,
                                                    ovfcnt, ovf, sbuf);
    k_decode<<<8, 1024, 0, stream>>>(sbuf, w2, b2, lnf_g, lnf_b, lnd_g, lnd_b,
                                     dw1, db1, dw2, db2, decRow);
    k_gather<<<24576, 256, 0, stream>>>(indices, decRow, out);
}

// Round 6
// 267.430 us; speedup vs baseline: 1.0644x; 1.0492x over previous
//
#include <hip/hip_runtime.h>
#include <math.h>

#define TT 8
#define NTOK 12288
#define DD 256
#define NNODE 8192
#define NNODES 32768
#define CLEN 16
#define CDIM 64
#define CHUNK 2048
#define H1 128

typedef __bf16 bf16x8 __attribute__((ext_vector_type(8)));
typedef float f32x4 __attribute__((ext_vector_type(4)));

__device__ __forceinline__ float gelu_exact(float v) {
    return 0.5f * v * (1.0f + erff(v * 0.70710678118654752f));
}

__device__ __forceinline__ ushort f2bf(float f) {
    uint u = __float_as_uint(f);
    u += 0x7FFFu + ((u >> 16) & 1u);
    return (ushort)(u >> 16);
}
__device__ __forceinline__ float bf2f(ushort h) {
    return __uint_as_float(((uint)h) << 16);
}

// ---- Kernel 0: single-block (1024 thr) split of wt = g.*w1 into bf16 hi/lo,
//      chunk-tiled [8][128 col][32 k]; u[c]=colsum(wt), v[c]=sum_k b[k]*w1[k,c]
//      via LDS reduce -> direct store (no atomics, no pre-zero needed). ----
__global__ __launch_bounds__(1024) void k_split_w1(
    const float* __restrict__ w1, const float* __restrict__ ln1_g,
    const float* __restrict__ ln1_b,
    ushort* __restrict__ w1pre, float* __restrict__ uvec, float* __restrict__ vvec)
{
    __shared__ float redU[8][128], redV[8][128];
    const int tid = threadIdx.x;
    const int c = tid & 127, q = tid >> 7;      // col, k-octet (32 k each)

    float su = 0.f, sv = 0.f;
    uint hb[16], lb[16];
    #pragma unroll
    for (int kk = 0; kk < 32; kk += 2) {
        const int k0 = q * 32 + kk;
        const float w0 = w1[k0 * 128 + c];
        const float w1v = w1[(k0 + 1) * 128 + c];
        const float wt0 = w0 * ln1_g[k0];
        const float wt1 = w1v * ln1_g[k0 + 1];
        const ushort h0 = f2bf(wt0), h1 = f2bf(wt1);
        const ushort l0 = f2bf(wt0 - bf2f(h0)), l1 = f2bf(wt1 - bf2f(h1));
        hb[kk >> 1] = (uint)h0 | ((uint)h1 << 16);
        lb[kk >> 1] = (uint)l0 | ((uint)l1 << 16);
        su += wt0 + wt1;
        sv += ln1_b[k0] * w0 + ln1_b[k0 + 1] * w1v;
    }
    ushort* dst = w1pre + ((q * 128 + c) << 5);
    #pragma unroll
    for (int u = 0; u < 4; ++u) {
        ((uint4*)dst)[u] = make_uint4(hb[u*4], hb[u*4+1], hb[u*4+2], hb[u*4+3]);
        ((uint4*)(dst + 32768))[u] = make_uint4(lb[u*4], lb[u*4+1], lb[u*4+2], lb[u*4+3]);
    }
    redU[q][c] = su;
    redV[q][c] = sv;
    __syncthreads();
    if (tid < 128) {
        float uu = 0.f, vv = 0.f;
        #pragma unroll
        for (int qq = 0; qq < 8; ++qq) { uu += redU[qq][tid]; vv += redV[qq][tid]; }
        uvec[tid] = uu;
        vvec[tid] = vv;
    }
}

// ---- Kernel 1: MFMA GEMM on RAW x (hi/lo bf16 split), LN folded into epilogue:
//      y[i,c] = r_i*(x@wt)[i,c] - r_i*m_i*u[c] + v[c]
// grid (64 rowblocks, 8 t), block 256 (4 waves). Block tile: 128 rows x 128 cols,
// each wave owns a 64x64 quadrant (acc 4x4). BK=32, 8 chunks.
// vs R4 (64x128 tile): -32% LDS-port traffic/FLOP, half the barrier groups,
// half the B L2 re-reads. Staging/split/epilogue logic identical to R4.
__global__ __launch_bounds__(256) void k_ln_gemm(
    const float* __restrict__ x, const int* __restrict__ indices,
    const ushort* __restrict__ w1pre,
    const float* __restrict__ uvec, const float* __restrict__ vvec,
    float* __restrict__ y,
    int* __restrict__ cnt, int* __restrict__ slot0, int* __restrict__ slotsx,
    int* __restrict__ ovfcnt, int* __restrict__ ovf)
{
    const int t = blockIdx.y;
    const int rowBase = blockIdx.x * 128;
    const int tid = threadIdx.x;

    // row stride 40 bf16 (80 B): conflict pattern identical to R4 (2-way max).
    __shared__ ushort Ah[128 * 40];   // 10 KiB
    __shared__ ushort Al[128 * 40];   // 10 KiB
    __shared__ ushort Bh[128 * 40];   // 10 KiB
    __shared__ ushort Bl[128 * 40];   // 10 KiB
    __shared__ float red[128][4][2];  // 4 KiB
    __shared__ float mS[128], rS[128];
    __shared__ float uS[128], vS[128];

    const float* xblk = x + ((size_t)t * NTOK + rowBase) * DD;

    // per-node row recording (128 rows of this block) + u/v staging
    if (tid < 128) {
        const int i = rowBase + tid;
        const int node = indices[t * NNODE + i];
        const int g = t * NNODES + node;
        const int pos = atomicAdd(&cnt[g], 1);
        if (pos == 0) slot0[g] = i;
        else if (pos <= 15) slotsx[(size_t)g * 15 + (pos - 1)] = i;
        else {
            const int op = atomicAdd(&ovfcnt[t], 1);
            ovf[t * NNODE + op] = (node << 13) | i;
        }
        uS[tid] = uvec[tid];
        vS[tid] = vvec[tid];
    }

    // B staging roles (unchanged from R4)
    const int bcol  = tid >> 1;      // B: one col
    const int bhalf = tid & 1;       // B: 16-k half

    const int lane = tid & 63;
    const int wv   = tid >> 6;
    const int wr   = wv >> 1;        // wave row-half (0/1)
    const int wc   = wv & 1;         // wave col-half (0/1)
    const int arow = lane & 15;      // frag index (A: row, B: col)
    const int kg   = lane >> 4;      // k-group 0..3

    f32x4 acc[4][4];
    #pragma unroll
    for (int rt = 0; rt < 4; ++rt)
        #pragma unroll
        for (int ct = 0; ct < 4; ++ct)
            acc[rt][ct] = (f32x4){0.f, 0.f, 0.f, 0.f};

    float stS[2] = {0.f, 0.f}, stSS[2] = {0.f, 0.f};

    for (int kc = 0; kc < 8; ++kc) {
        // ---- stage A: 2 slots/thread (512 row-octet slots), stats + hi/lo split ----
        #pragma unroll
        for (int u = 0; u < 2; ++u) {
            const int slot = tid + u * 256;
            const int q = slot >> 7, row = slot & 127;
            const int k0 = kc * 32 + q * 8;
            const float* xr = xblk + (size_t)row * DD + k0;
            const float4 v0 = *(const float4*)xr;
            const float4 v1 = *(const float4*)(xr + 4);
            const float xv[8] = {v0.x, v0.y, v0.z, v0.w, v1.x, v1.y, v1.z, v1.w};
            uint hp[4], lp[4];
            #pragma unroll
            for (int j = 0; j < 4; ++j) {
                const float a0 = xv[2*j], a1 = xv[2*j+1];
                stS[u]  += a0 + a1;
                stSS[u] += a0*a0 + a1*a1;
                const ushort h0 = f2bf(a0), h1 = f2bf(a1);
                const ushort l0 = f2bf(a0 - bf2f(h0)), l1 = f2bf(a1 - bf2f(h1));
                hp[j] = (uint)h0 | ((uint)h1 << 16);
                lp[j] = (uint)l0 | ((uint)l1 << 16);
            }
            *(uint4*)&Ah[row * 40 + q * 8] = make_uint4(hp[0], hp[1], hp[2], hp[3]);
            *(uint4*)&Al[row * 40 + q * 8] = make_uint4(lp[0], lp[1], lp[2], lp[3]);
        }
        // ---- stage B: copy pre-split g.*w1 chunk [128 col][32 k] hi/lo -> LDS ----
        {
            const ushort* srcH = w1pre + ((kc * 128 + bcol) * 32 + bhalf * 16);
            const uint4 h0 = *(const uint4*)srcH;
            const uint4 h1 = *(const uint4*)(srcH + 8);
            const uint4 l0 = *(const uint4*)(srcH + 32768);
            const uint4 l1 = *(const uint4*)(srcH + 32768 + 8);
            const int d = bcol * 40 + bhalf * 16;
            *(uint4*)&Bh[d]     = h0;
            *(uint4*)&Bh[d + 8] = h1;
            *(uint4*)&Bl[d]     = l0;
            *(uint4*)&Bl[d + 8] = l1;
        }
        __syncthreads();

        // ---- frags + MFMA (4x4 quadrant per wave) ----
        bf16x8 a_h[4], a_l[4], b_h[4], b_l[4];
        #pragma unroll
        for (int rt = 0; rt < 4; ++rt) {
            const int o = (wr * 64 + rt * 16 + arow) * 40 + kg * 8;
            a_h[rt] = *(const bf16x8*)&Ah[o];
            a_l[rt] = *(const bf16x8*)&Al[o];
        }
        #pragma unroll
        for (int ct = 0; ct < 4; ++ct) {
            const int o = (wc * 64 + ct * 16 + arow) * 40 + kg * 8;
            b_h[ct] = *(const bf16x8*)&Bh[o];
            b_l[ct] = *(const bf16x8*)&Bl[o];
        }
        #pragma unroll
        for (int rt = 0; rt < 4; ++rt)
            #pragma unroll
            for (int ct = 0; ct < 4; ++ct) {
                acc[rt][ct] = __builtin_amdgcn_mfma_f32_16x16x32_bf16(a_h[rt], b_h[ct], acc[rt][ct], 0, 0, 0);
                acc[rt][ct] = __builtin_amdgcn_mfma_f32_16x16x32_bf16(a_h[rt], b_l[ct], acc[rt][ct], 0, 0, 0);
                acc[rt][ct] = __builtin_amdgcn_mfma_f32_16x16x32_bf16(a_l[rt], b_h[ct], acc[rt][ct], 0, 0, 0);
            }
        __syncthreads();
    }

    // ---- reduce LN stats (4 octet-slots per row) ----
    #pragma unroll
    for (int u = 0; u < 2; ++u) {
        const int slot = tid + u * 256;
        red[slot & 127][slot >> 7][0] = stS[u];
        red[slot & 127][slot >> 7][1] = stSS[u];
    }
    __syncthreads();
    if (tid < 128) {
        const float s  = red[tid][0][0] + red[tid][1][0] + red[tid][2][0] + red[tid][3][0];
        const float ss = red[tid][0][1] + red[tid][1][1] + red[tid][2][1] + red[tid][3][1];
        const float m = s * (1.0f / 256.0f);
        const float var = ss * (1.0f / 256.0f) - m * m;
        mS[tid] = m;
        rS[tid] = rsqrtf(var + 1e-5f);
    }
    __syncthreads();

    // ---- epilogue: LN correction + store. C/D layout col=lane&15, row=(lane>>4)*4+reg ----
    #pragma unroll
    for (int rt = 0; rt < 4; ++rt) {
        const int rloc = wr * 64 + rt * 16 + kg * 4;
        #pragma unroll
        for (int ct = 0; ct < 4; ++ct) {
            const int gcol = wc * 64 + ct * 16 + arow;
            const float uu = uS[gcol];
            const float vb = vS[gcol];
            float* dst = y + (((size_t)t * NNODE + rowBase + rloc) << 7) + gcol;
            #pragma unroll
            for (int j = 0; j < 4; ++j) {
                const float m = mS[rloc + j], r = rS[rloc + j];
                dst[(size_t)j << 7] = r * (acc[rt][ct][j] - m * uu) + vb;
            }
        }
    }
}

// ---- Kernel 2: per-node sums -> gelu -> chunk sum into sbuf ----
// grid (sub 32, l 16, t 8) = 4096 blocks, block 256 = 2 node-lanes x 128 cols.
__global__ __launch_bounds__(256) void k_node_sum(
    const float* __restrict__ y, const float* __restrict__ b1,
    const int* __restrict__ cnt, const int* __restrict__ slot0,
    const int* __restrict__ slotsx,
    const int* __restrict__ ovfcnt, const int* __restrict__ ovf,
    float* __restrict__ sbuf)
{
    const int tid = threadIdx.x;
    const int sub = blockIdx.x, l = blockIdx.y, t = blockIdx.z;
    const int base = l * CHUNK + sub * 64;       // first node of this block

    __shared__ int cS[64], s0S[64];
    __shared__ float redc[256];

    if (tid < 64) {
        cS[tid]  = cnt[t * NNODES + base + tid];
        s0S[tid] = slot0[t * NNODES + base + tid];
    }
    __syncthreads();

    const int c = tid & 127;     // column
    const int h = tid >> 7;      // node parity
    const float b1c = b1[c];
    const float geluB = gelu_exact(b1c);
    const float* ybase = y + (((size_t)t * NNODE) << 7) + c;

    float cs = 0.f;
    int zc = 0;

    for (int p = 0; p < 32; ++p) {
        const int nl = p * 2 + h;          // node-local 0..63 (uniform per wave)
        const int n = cS[nl];
        if (n == 0) { ++zc; continue; }
        float acc = b1c + ybase[(size_t)s0S[nl] << 7];
        if (n > 1) {
            const int m = n < 16 ? n : 16;
            const int* sx = slotsx + (size_t)(t * NNODES + base + nl) * 15;
            for (int j = 0; j < m - 1; ++j)
                acc += ybase[(size_t)sx[j] << 7];
            if (n > 16) {                   // ultra-rare overflow path
                int oc = ovfcnt[t]; if (oc > NNODE) oc = NNODE;
                const int node = base + nl;
                for (int e = 0; e < oc; ++e) {
                    const int v = ovf[t * NNODE + e];
                    if ((v >> 13) == node) acc += ybase[(size_t)(v & 8191) << 7];
                }
            }
        }
        cs += gelu_exact(acc);
    }
    cs += (float)zc * geluB;

    redc[tid] = cs;
    __syncthreads();
    if (tid < 128)
        atomicAdd(&sbuf[(t * CLEN + l) * H1 + c], redc[tid] + redc[tid + 128]);
}

// ---- Kernel 3: comp = sbuf @ w2 + 2048*b2 ; lnf ; lnd ; decoder MLP -> decRow ----
// grid 8 (per t), block 1024. wave == one 64-wide comp row -> shfl butterflies.
__global__ __launch_bounds__(1024) void k_decode(
    const float* __restrict__ sbuf, const float* __restrict__ w2,
    const float* __restrict__ b2,
    const float* __restrict__ lnf_g, const float* __restrict__ lnf_b,
    const float* __restrict__ lnd_g, const float* __restrict__ lnd_b,
    const float* __restrict__ dw1, const float* __restrict__ db1,
    const float* __restrict__ dw2, const float* __restrict__ db2,
    float* __restrict__ decRow)
{
    const int t = blockIdx.x, tid = threadIdx.x;
    __shared__ float wbuf[8192];          // staged weight chunk (32 KiB)
    __shared__ float sb[CLEN * H1];       // staged sbuf[t] (8 KiB)
    __shared__ float vv[CLEN][CDIM];
    __shared__ float hh[CLEN][H1];
    __shared__ float redA[16], redB[16];

    // stage sbuf[t] (2048 f) + w2 (8192 f)
    if (tid < 512) *(float4*)&sb[tid * 4] = *(const float4*)(sbuf + t * CLEN * H1 + tid * 4);
    #pragma unroll
    for (int u = 0; u < 2; ++u) {
        const int j4 = (tid + u * 1024) * 4;
        *(float4*)&wbuf[j4] = *(const float4*)(w2 + j4);
    }
    __syncthreads();

    // 1) comp element per thread: a = (sb @ w2)[l,cc] + CHUNK*b2[cc]
    const int l = tid >> 6, cc = tid & 63;   // wave == row l
    float a = (float)CHUNK * b2[cc];
    {
        const float* sp = sb + l * H1;
        for (int k = 0; k < H1; ++k) a += sp[k] * wbuf[k * CDIM + cc];
    }
    __syncthreads();                          // wbuf (w2) free

    // stage dw1 (8192 f) while lnf partials reduce
    #pragma unroll
    for (int u = 0; u < 2; ++u) {
        const int j4 = (tid + u * 1024) * 4;
        *(float4*)&wbuf[j4] = *(const float4*)(dw1 + j4);
    }
    // 2) lnf over 1024: wave butterfly (= row sum) then 16 partials
    float s = a, ss = a * a;
    #pragma unroll
    for (int off = 1; off < 64; off <<= 1) {
        s  += __shfl_xor(s, off);
        ss += __shfl_xor(ss, off);
    }
    if ((tid & 63) == 0) { redA[tid >> 6] = s; redB[tid >> 6] = ss; }
    __syncthreads();                          // partials + dw1 staged

    float st = 0.f, sst = 0.f;
    #pragma unroll
    for (int w = 0; w < 16; ++w) { st += redA[w]; sst += redB[w]; }
    const float mG = st * (1.0f / 1024.0f);
    const float rG = rsqrtf(sst * (1.0f / 1024.0f) - mG * mG + 1e-5f);
    const float vln = (a - mG) * rG * lnf_g[tid] + lnf_b[tid];

    // 3) lnd per 64-wide row: pure wave butterfly
    float s2 = vln, ss2 = vln * vln;
    #pragma unroll
    for (int off = 1; off < 64; off <<= 1) {
        s2  += __shfl_xor(s2, off);
        ss2 += __shfl_xor(ss2, off);
    }
    const float m2 = s2 * (1.0f / 64.0f);
    const float r2 = rsqrtf(ss2 * (1.0f / 64.0f) - m2 * m2 + 1e-5f);
    vv[l][cc] = (vln - m2) * r2 * lnd_g[cc] + lnd_b[cc];
    __syncthreads();                          // vv ready, wbuf = dw1 ready

    // 4) hh = gelu(vv @ dw1 + db1): 2048 outputs, 2 per thread
    #pragma unroll
    for (int u = 0; u < 2; ++u) {
        const int j = tid + u * 1024;
        const int lh = j >> 7, ch = j & 127;
        float acc = db1[ch];
        for (int k = 0; k < CDIM; ++k) acc += vv[lh][k] * wbuf[k * H1 + ch];
        hh[lh][ch] = gelu_exact(acc);
    }
    __syncthreads();                          // hh ready, wbuf free

    // 5) decRow = hh @ dw2 + db2, dw2 staged in four 64-col chunks (128x64 each)
    for (int chk = 0; chk < 4; ++chk) {
        const int c0 = chk * 64;
        #pragma unroll
        for (int u = 0; u < 2; ++u) {
            const int e = tid + u * 1024;         // 0..2047
            const int k = e >> 4, cq = e & 15;    // k<128, 16 float4 per row
            *(float4*)&wbuf[k * 64 + cq * 4] =
                *(const float4*)(dw2 + (size_t)k * DD + c0 + cq * 4);
        }
        __syncthreads();
        float acc = db2[c0 + cc];
        for (int k = 0; k < H1; ++k) acc += hh[l][k] * wbuf[k * 64 + cc];
        decRow[(t * CLEN + l) * DD + c0 + cc] = acc;
        __syncthreads();
    }
}

// ---- Kernel 4: out[t,i,:] = decRow[t, idx[t,i]>>11, :] for i<8192 else 0 ----
// grid-stride (4096 blocks x 6 iters), nontemporal stores (write-once stream).
__global__ __launch_bounds__(256) void k_gather(
    const int* __restrict__ indices, const float* __restrict__ decRow,
    float* __restrict__ out)
{
    const int tid = threadIdx.x;
    for (int b = blockIdx.x; b < 24576; b += 4096) {
        const int r = b * 4 + (tid >> 6);
        const int c4 = tid & 63;
        const int t = r / NTOK;
        const int i = r - t * NTOK;
        f32x4 v = (f32x4){0.f, 0.f, 0.f, 0.f};
        if (i < NNODE) {
            const int node = indices[t * NNODE + i];
            const int l = node >> 11;
            v = *(const f32x4*)(decRow + (t * CLEN + l) * DD + c4 * 4);
        }
        __builtin_nontemporal_store(v, (f32x4*)(out + (size_t)r * DD + c4 * 4));
    }
}

extern "C" void kernel_launch(void* const* d_in, const int* in_sizes, int n_in,
                              void* d_out, int out_size, void* d_ws, size_t ws_size,
                              hipStream_t stream)
{
    const float* x       = (const float*)d_in[0];
    const int*   indices = (const int*)d_in[1];
    const float* ln1_g   = (const float*)d_in[2];
    const float* ln1_b   = (const float*)d_in[3];
    const float* w1      = (const float*)d_in[4];
    const float* b1      = (const float*)d_in[5];
    const float* w2      = (const float*)d_in[6];
    const float* b2      = (const float*)d_in[7];
    const float* lnf_g   = (const float*)d_in[8];
    const float* lnf_b   = (const float*)d_in[9];
    const float* lnd_g   = (const float*)d_in[10];
    const float* lnd_b   = (const float*)d_in[11];
    const float* dw1     = (const float*)d_in[12];
    const float* db1     = (const float*)d_in[13];
    const float* dw2     = (const float*)d_in[14];
    const float* db2     = (const float*)d_in[15];
    float* out = (float*)d_out;

    char* ws = (char*)d_ws;
    // zeroed region: cnt (1 MiB) + ovfcnt (32 B) + sbuf (64 KiB)
    int*    cnt    = (int*)ws;                            // 0x000000, 1 MiB
    int*    ovfcnt = (int*)(ws + 0x100000);               // 32 B
    float*  sbuf   = (float*)(ws + 0x100020);             // 64 KiB -> ends 0x110020
    float*  uvec   = (float*)(ws + 0x110020);             // 512 B (written directly)
    float*  vvec   = (float*)(ws + 0x110220);             // 512 B
    int*    slot0  = (int*)(ws + 0x120000);               // 1 MiB
    int*    slotsx = (int*)(ws + 0x220000);               // 15 MiB -> ends 0x1120000
    ushort* w1pre  = (ushort*)(ws + 0x1120000);           // 128 KiB (hi 64K + lo 64K)
    int*    ovf    = (int*)(ws + 0x11E0000);              // 256 KiB
    float*  decRow = (float*)(ws + 0x1220000);            // 128 KiB
    float*  y      = (float*)(ws + 0x1240000);            // 32 MiB

    hipMemsetAsync(ws, 0, 0x110020, stream);

    k_split_w1<<<1, 1024, 0, stream>>>(w1, ln1_g, ln1_b, w1pre, uvec, vvec);
    k_ln_gemm<<<dim3(64, 8), 256, 0, stream>>>(x, indices, w1pre, uvec, vvec, y,
                                               cnt, slot0, slotsx, ovfcnt, ovf);
    k_node_sum<<<dim3(32, 16, 8), 256, 0, stream>>>(y, b1, cnt, slot0, slotsx,
                                                    ovfcnt, ovf, sbuf);
    k_decode<<<8, 1024, 0, stream>>>(sbuf, w2, b2, lnf_g, lnf_b, lnd_g, lnd_b,
                                     dw1, db1, dw2, db2, decRow);
    k_gather<<<4096, 256, 0, stream>>>(indices, decRow, out);
}